// Round 5
// baseline (387.108 us; speedup 1.0000x reference)
//
#include <hip/hip_runtime.h>
#include <math.h>

#define NS   8      // samples
#define CC   256    // input channels
#define PP   961    // H*W
#define MM   7688   // NS*PP nodes
#define MP   7744   // MM padded to 64
#define HID  512
#define OUTC 256

typedef _Float16 h16;
using half8   = __attribute__((ext_vector_type(8))) _Float16;
using floatx4 = __attribute__((ext_vector_type(4))) float;

#define AS1 __attribute__((address_space(1)))
#define AS3 __attribute__((address_space(3)))

// deg = 963 for b in {0,7}, 964 otherwise; dinv = deg^-0.5
__device__ __forceinline__ float dinv_of(int b) {
    return (b == 0 || b == NS - 1) ? 0.0322245515f : 0.0322078318f;
}

// Single-use grid barrier: 1 atomic arrive per block, device-scope fences.
// Safe because hipLaunchCooperativeKernel guarantees co-residency.
__device__ __forceinline__ void grid_sync_once(unsigned* ctr, unsigned nblk) {
    __syncthreads();                       // drains each wave's vmem before arrive
    if (threadIdx.x == 0) {
        __threadfence();                   // release: L2 writeback, device scope
        __hip_atomic_fetch_add(ctr, 1u, __ATOMIC_ACQ_REL, __HIP_MEMORY_SCOPE_AGENT);
        while (__hip_atomic_load(ctr, __ATOMIC_ACQUIRE, __HIP_MEMORY_SCOPE_AGENT) < nblk)
            __builtin_amdgcn_s_sleep(2);
        __threadfence();                   // acquire: invalidate stale cache lines
    }
    __syncthreads();
}

// One 64x64 output tile: C = A @ B^T (raw, no bias/act), fp16 in / fp32 acc.
// BK=64, XOR-swizzled LDS chunks. DO_SUM: per-sample column sums of v -> atomicAdd S.
template<int KD, bool DO_SUM, typename OutT>
__device__ __forceinline__ void gemm_tile(
    const h16* __restrict__ A,    // [MP][KD]
    const h16* __restrict__ B,    // [Nc][KD]
    OutT* __restrict__ C,         // [M][Nc]
    float* __restrict__ S,        // [NS][Nc]
    int m0, int n0, int Nc, int M, h16* As, h16* Bs)
{
    int tid = threadIdx.x, wave = tid >> 6, lane = tid & 63;
    // staging: per instr, 8 rows x 8 chunks(16B); lane l -> row +(l>>3), slot l&7,
    // fetches global chunk c = (l&7)^(l>>3) so LDS slot s of row r holds chunk s^(r&7).
    int sro = lane >> 3;
    int sch = (lane & 7) ^ sro;
    const h16* ga0 = A + (size_t)(m0 + wave * 16 + sro) * KD + sch * 8;
    const h16* gb0 = B + (size_t)(n0 + wave * 16 + sro) * KD + sch * 8;
    h16* la0 = &As[(wave * 16) * 64];
    h16* la1 = &As[(wave * 16 + 8) * 64];
    h16* lb0 = &Bs[(wave * 16) * 64];
    h16* lb1 = &Bs[(wave * 16 + 8) * 64];
    int fr = lane & 15, fq = lane >> 4;
    floatx4 acc[4] = {{0.f,0.f,0.f,0.f},{0.f,0.f,0.f,0.f},{0.f,0.f,0.f,0.f},{0.f,0.f,0.f,0.f}};
    for (int kk = 0; kk < KD; kk += 64) {
        __builtin_amdgcn_global_load_lds((const AS1 void*)(const void*)(ga0 + kk),
                                         (AS3 void*)(void*)la0, 16, 0, 0);
        __builtin_amdgcn_global_load_lds((const AS1 void*)(const void*)(ga0 + 8 * KD + kk),
                                         (AS3 void*)(void*)la1, 16, 0, 0);
        __builtin_amdgcn_global_load_lds((const AS1 void*)(const void*)(gb0 + kk),
                                         (AS3 void*)(void*)lb0, 16, 0, 0);
        __builtin_amdgcn_global_load_lds((const AS1 void*)(const void*)(gb0 + 8 * KD + kk),
                                         (AS3 void*)(void*)lb1, 16, 0, 0);
        __syncthreads();
        #pragma unroll
        for (int ks = 0; ks < 2; ++ks) {
            int slot = (ks * 4 + fq) ^ (fr & 7);
            half8 bf = *(const half8*)&Bs[(wave * 16 + fr) * 64 + slot * 8];
            #pragma unroll
            for (int mb = 0; mb < 4; ++mb) {
                half8 af = *(const half8*)&As[(mb * 16 + fr) * 64 + slot * 8];
                acc[mb] = __builtin_amdgcn_mfma_f32_16x16x32_f16(af, bf, acc[mb], 0, 0, 0);
            }
        }
        __syncthreads();
    }
    int col = n0 + wave * 16 + fr;
    float s_lo = 0.f, s_hi = 0.f;
    int blo = m0 / 961;
    int mcut = (blo + 1) * 961;
    #pragma unroll
    for (int mb = 0; mb < 4; ++mb) {
        #pragma unroll
        for (int r = 0; r < 4; ++r) {
            int m = m0 + mb * 16 + fq * 4 + r;
            if (m < M) {
                float v = acc[mb][r];
                C[(size_t)m * Nc + col] = (OutT)v;
                if (DO_SUM) { if (m < mcut) s_lo += v; else s_hi += v; }
            }
        }
    }
    if (DO_SUM) {
        s_lo += __shfl_xor(s_lo, 16);
        s_lo += __shfl_xor(s_lo, 32);
        s_hi += __shfl_xor(s_hi, 16);
        s_hi += __shfl_xor(s_hi, 32);
        if (fq == 0) {
            atomicAdd(&S[blo * Nc + col], s_lo);
            int bhi = (m0 + 63) / 961;
            if (bhi != blo && bhi < NS) atomicAdd(&S[bhi * Nc + col], s_hi);
        }
    }
}

// The whole pipeline in one cooperative kernel.
// S0: W->fp16, zero SZ/SY, transpose-cast x -> Xt[m=(b,p)][c]
// S1: Z = Xt @ W1^T  (+ per-sample colsums SZ)
// S2: H1 = lrelu( b1 + db*( db*(SZ+Z) + dm*Z[-PP] + dp*Z[+PP] ) )  fp16
// S3: Y = H1 @ W2^T  (+ colsums SY)
// S4: out = max_b lrelu( b2 + db*( db*(SY+Y) + dm*Y[-PP] + dp*Y[+PP] ) )
__global__ __launch_bounds__(256, 2) void fused(
    const float* __restrict__ x,
    const float* __restrict__ W1, const float* __restrict__ b1v,
    const float* __restrict__ W2, const float* __restrict__ b2v,
    h16* __restrict__ w1h, h16* __restrict__ w2h,
    h16* __restrict__ Xt, h16* __restrict__ Z, float* __restrict__ SZ,
    h16* __restrict__ H1, float* __restrict__ Y, float* __restrict__ SY,
    float* __restrict__ out, unsigned* __restrict__ bars)
{
    __shared__ __align__(16) unsigned char smem[16384];
    h16* As = (h16*)smem;
    h16* Bs = (h16*)(smem + 8192);
    int tid = threadIdx.x, blk = blockIdx.x;
    int nblk = gridDim.x;
    int gstride = nblk * 256;
    int g = blk * 256 + tid;

    // ---------- stage 0 ----------
    for (int i = g; i < HID * CC / 2; i += gstride) {    // 65536 float2 per matrix
        float2 v1 = *(const float2*)(W1 + 2 * i);
        w1h[2 * i] = (h16)v1.x; w1h[2 * i + 1] = (h16)v1.y;
        float2 v2 = *(const float2*)(W2 + 2 * i);
        w2h[2 * i] = (h16)v2.x; w2h[2 * i + 1] = (h16)v2.y;
    }
    for (int i = g; i < NS * (HID + OUTC); i += gstride) {
        if (i < NS * HID) SZ[i] = 0.f; else SY[i - NS * HID] = 0.f;
    }
    {   // transpose-cast x[b,c,p] -> Xt[(b,p),c], 32x32 tiles
        h16 (*tr)[33] = (h16(*)[33])smem;
        int j = tid & 31, i0 = tid >> 5;
        for (int t = blk; t < 31 * 8 * NS; t += nblk) {
            int b = t & 7, ct = (t >> 3) & 7, pt = t >> 6;
            int p0 = pt * 32, c0 = ct * 32;
            int p = p0 + j;
            __syncthreads();
            #pragma unroll
            for (int r = 0; r < 4; ++r) {
                int c = c0 + i0 + r * 8;
                float v = (p < PP) ? x[((size_t)b * CC + c) * PP + p] : 0.f;
                tr[i0 + r * 8][j] = (h16)v;
            }
            __syncthreads();
            #pragma unroll
            for (int r = 0; r < 4; ++r) {
                int ii = tid & 31;
                int jj = (tid >> 5) + r * 8;
                int pw = p0 + jj;
                if (pw < PP)
                    Xt[((size_t)b * PP + pw) * CC + c0 + ii] = tr[ii][jj];
            }
        }
    }
    grid_sync_once(bars + 0, nblk);

    // ---------- stage 1: Z = Xt @ W1^T ----------
    for (int t = blk; t < 121 * (HID / 64); t += nblk) {
        int bx = t % 121, by = t / 121;
        gemm_tile<CC, true, h16>(Xt, w1h, Z, SZ, bx * 64, by * 64, HID, MM, As, Bs);
    }
    grid_sync_once(bars + 1, nblk);

    // ---------- stage 2: apply1 ----------
    for (int id8 = g; id8 < MM * HID / 8; id8 += gstride) {
        int m = id8 >> 6;
        int h0 = (id8 & 63) * 8;
        int b = m / PP;
        float db = dinv_of(b);
        float dm = (b > 0)      ? dinv_of(b - 1) : 0.f;
        float dp = (b < NS - 1) ? dinv_of(b + 1) : 0.f;
        size_t base = (size_t)m * HID + h0;
        half8 zv = {(h16)0,(h16)0,(h16)0,(h16)0,(h16)0,(h16)0,(h16)0,(h16)0};
        half8 hb = *(const half8*)(Z + base);
        half8 hm = (b > 0)      ? *(const half8*)(Z + base - (size_t)PP * HID) : zv;
        half8 hp = (b < NS - 1) ? *(const half8*)(Z + base + (size_t)PP * HID) : zv;
        float4 sz0 = *(const float4*)(SZ + b * HID + h0);
        float4 sz1 = *(const float4*)(SZ + b * HID + h0 + 4);
        float4 bb0 = *(const float4*)(b1v + h0);
        float4 bb1 = *(const float4*)(b1v + h0 + 4);
        float szs[8] = {sz0.x, sz0.y, sz0.z, sz0.w, sz1.x, sz1.y, sz1.z, sz1.w};
        float bbs[8] = {bb0.x, bb0.y, bb0.z, bb0.w, bb1.x, bb1.y, bb1.z, bb1.w};
        half8 o;
        #pragma unroll
        for (int jv = 0; jv < 8; ++jv) {
            float v = db * (szs[jv] + (float)hb[jv])
                    + dm * (float)hm[jv] + dp * (float)hp[jv];
            float z2 = db * v + bbs[jv];
            z2 = (z2 >= 0.f) ? z2 : 0.01f * z2;
            o[jv] = (h16)z2;
        }
        *(half8*)(H1 + base) = o;
    }
    grid_sync_once(bars + 2, nblk);

    // ---------- stage 3: Y = H1 @ W2^T ----------
    for (int t = blk; t < 121 * (OUTC / 64); t += nblk) {
        int bx = t % 121, by = t / 121;
        gemm_tile<HID, true, float>(H1, w2h, Y, SY, bx * 64, by * 64, OUTC, MM, As, Bs);
    }
    grid_sync_once(bars + 3, nblk);

    // ---------- stage 4: final_max ----------
    {
        float (*tf)[33] = (float(*)[33])smem;
        int i = tid & 31, j0 = tid >> 5;
        for (int t = blk; t < 31 * 8; t += nblk) {
            int pt = t % 31, ot = t / 31;
            int p0 = pt * 32, o0 = ot * 32;
            int o = o0 + i;
            float bias = b2v[o];
            __syncthreads();
            #pragma unroll
            for (int r = 0; r < 4; ++r) {
                int j = j0 + r * 8;
                int p = p0 + j;
                float vmax = -INFINITY;
                if (p < PP) {
                    float y[NS];
                    #pragma unroll
                    for (int b = 0; b < NS; ++b)
                        y[b] = Y[((size_t)b * PP + p) * OUTC + o];
                    #pragma unroll
                    for (int b = 0; b < NS; ++b) {
                        float db = dinv_of(b);
                        float a = db * (SY[b * OUTC + o] + y[b]);
                        if (b > 0)      a += dinv_of(b - 1) * y[b - 1];
                        if (b < NS - 1) a += dinv_of(b + 1) * y[b + 1];
                        float z2 = db * a + bias;
                        z2 = (z2 >= 0.f) ? z2 : 0.01f * z2;
                        vmax = fmaxf(vmax, z2);
                    }
                }
                tf[j][i] = vmax;
            }
            __syncthreads();
            #pragma unroll
            for (int r = 0; r < 4; ++r) {
                int ii = (tid >> 5) + r * 8;
                int jj = tid & 31;
                int pw = p0 + jj;
                if (pw < PP)
                    out[(size_t)(o0 + ii) * PP + pw] = tf[jj][ii];
            }
        }
    }
}

extern "C" void kernel_launch(void* const* d_in, const int* in_sizes, int n_in,
                              void* d_out, int out_size, void* d_ws, size_t ws_size,
                              hipStream_t stream) {
    const float* x  = (const float*)d_in[0];
    const float* W1 = (const float*)d_in[1];
    const float* b1 = (const float*)d_in[2];
    const float* W2 = (const float*)d_in[3];
    const float* b2 = (const float*)d_in[4];
    float* out = (float*)d_out;
    float* ws  = (float*)d_ws;

    // workspace layout (float offsets, 16B-aligned)
    unsigned* bars = (unsigned*)ws;              // 4 counters (memset to 0 below)
    h16*  w1h = (h16*)(ws + 16);                 // 131072 h =  65,536 f
    h16*  w2h = (h16*)(ws + 65552);              // 131072 h
    h16*  Xt  = (h16*)(ws + 131088);             // MP*CC  h =   991,232 f
    h16*  Z   = (h16*)(ws + 1122320);            // MP*HID h = 1,982,464 f
    float* SZ = ws + 3104784;                    //     4,096 f
    h16*  H1  = (h16*)(ws + 3108880);            // MP*HID h = 1,982,464 f (pad rows stay poison: finite)
    float* Y  = ws + 5091344;                    // MM*OUTC f = 1,968,128 f
    float* SY = ws + 7059472;                    //     2,048 f -> end 7,061,520 f (28.2 MB)

    hipMemsetAsync(bars, 0, 4 * sizeof(unsigned), stream);

    int maxb = 0;
    hipOccupancyMaxActiveBlocksPerMultiprocessor(&maxb, fused, 256, 0);
    if (maxb < 1) maxb = 1;
    int grid = maxb * 256;
    if (grid > 512) grid = 512;

    void* args[] = { (void*)&x, (void*)&W1, (void*)&b1, (void*)&W2, (void*)&b2,
                     (void*)&w1h, (void*)&w2h, (void*)&Xt, (void*)&Z, (void*)&SZ,
                     (void*)&H1, (void*)&Y, (void*)&SY, (void*)&out, (void*)&bars };
    hipLaunchCooperativeKernel((void*)fused, dim3(grid), dim3(256), args, 0, stream);
}

// Round 6
// 101.602 us; speedup vs baseline: 3.8101x; 3.8101x over previous
//
#include <hip/hip_runtime.h>
#include <math.h>

#define NS   8      // samples
#define CC   256    // input channels
#define PP   961    // H*W
#define MM   7688   // NS*PP nodes
#define MP   7744   // MM padded to 64
#define HID  512
#define OUTC 256

typedef _Float16 h16;
using half8   = __attribute__((ext_vector_type(8))) _Float16;
using floatx4 = __attribute__((ext_vector_type(4))) float;

#define AS1 __attribute__((address_space(1)))
#define AS3 __attribute__((address_space(3)))

// deg = 963 for b in {0,7}, 964 otherwise; dinv = deg^-0.5
__device__ __forceinline__ float dinv_of(int b) {
    return (b == 0 || b == NS - 1) ? 0.0322245515f : 0.0322078318f;
}

// K0 prep: [0,256): W1/W2 -> fp16; [256,2240): transpose-cast x -> Xt; [2240,2264): zero SZ/SY
__global__ void prep(const float* __restrict__ W1, const float* __restrict__ W2,
                     h16* __restrict__ w1h, h16* __restrict__ w2h,
                     const float* __restrict__ x, h16* __restrict__ Xt,
                     float* __restrict__ SZ, float* __restrict__ SY) {
    int blk = blockIdx.x, tid = threadIdx.x;
    if (blk < 256) {
        bool second = blk >= 128;
        const float* src = second ? W2 : W1;
        h16* dst = second ? w2h : w1h;
        int i = ((blk & 127) * 256 + tid) * 4;
        float4 v = *(const float4*)(src + i);
        dst[i + 0] = (h16)v.x; dst[i + 1] = (h16)v.y;
        dst[i + 2] = (h16)v.z; dst[i + 3] = (h16)v.w;
    } else if (blk < 2240) {
        // transpose-cast one 32(c) x 32(p) tile of sample b
        __shared__ h16 tr[32][33];
        int t = blk - 256;                       // < 1984 = 31(pt) * 8(ct) * 8(b)
        int b = t & 7, ct = (t >> 3) & 7, pt = t >> 6;
        int p0 = pt * 32, c0 = ct * 32;
        int j = tid & 31, i0 = tid >> 5;
        int p = p0 + j;
        #pragma unroll
        for (int r = 0; r < 4; ++r) {
            int c = c0 + i0 + r * 8;
            float v = (p < PP) ? x[((size_t)b * CC + c) * PP + p] : 0.f;
            tr[i0 + r * 8][j] = (h16)v;
        }
        __syncthreads();
        #pragma unroll
        for (int r = 0; r < 4; ++r) {
            int ii = tid & 31;
            int jj = (tid >> 5) + r * 8;
            int pw = p0 + jj;
            if (pw < PP)
                Xt[((size_t)b * PP + pw) * CC + c0 + ii] = tr[ii][jj];
        }
    } else {
        int i = (blk - 2240) * 256 + tid;        // < 6144
        if (i < NS * HID) SZ[i] = 0.f;
        else SY[i - NS * HID] = 0.f;
    }
}

// K1: MFMA GEMM, 64x64 tile, BK=64, XOR-swizzled LDS chunks, fp16 in / fp32 acc.
// ACT: v = lrelu(acc + bias). DO_SUM: per-sample column sums of v -> atomicAdd S.
template<int KD, bool ACT, bool DO_SUM, typename OutT>
__global__ __launch_bounds__(256) void mfma_gemm(
    const h16* __restrict__ A,    // [MP][KD]
    const h16* __restrict__ B,    // [Nc][KD]
    const float* __restrict__ bias,
    OutT* __restrict__ C,         // [M][Nc]
    float* __restrict__ S,        // [NS][Nc]
    int M, int Nc)
{
    __shared__ __align__(16) h16 As[64 * 64];
    __shared__ __align__(16) h16 Bs[64 * 64];
    int tid = threadIdx.x, wave = tid >> 6, lane = tid & 63;
    int m0 = blockIdx.x * 64, n0 = blockIdx.y * 64;
    int sro = lane >> 3;
    int sch = (lane & 7) ^ sro;
    const h16* ga0 = A + (size_t)(m0 + wave * 16 + sro) * KD + sch * 8;
    const h16* gb0 = B + (size_t)(n0 + wave * 16 + sro) * KD + sch * 8;
    h16* la0 = &As[(wave * 16) * 64];
    h16* la1 = &As[(wave * 16 + 8) * 64];
    h16* lb0 = &Bs[(wave * 16) * 64];
    h16* lb1 = &Bs[(wave * 16 + 8) * 64];
    int fr = lane & 15, fq = lane >> 4;
    floatx4 acc[4] = {{0.f,0.f,0.f,0.f},{0.f,0.f,0.f,0.f},{0.f,0.f,0.f,0.f},{0.f,0.f,0.f,0.f}};
    for (int kk = 0; kk < KD; kk += 64) {
        __builtin_amdgcn_global_load_lds((const AS1 void*)(const void*)(ga0 + kk),
                                         (AS3 void*)(void*)la0, 16, 0, 0);
        __builtin_amdgcn_global_load_lds((const AS1 void*)(const void*)(ga0 + 8 * KD + kk),
                                         (AS3 void*)(void*)la1, 16, 0, 0);
        __builtin_amdgcn_global_load_lds((const AS1 void*)(const void*)(gb0 + kk),
                                         (AS3 void*)(void*)lb0, 16, 0, 0);
        __builtin_amdgcn_global_load_lds((const AS1 void*)(const void*)(gb0 + 8 * KD + kk),
                                         (AS3 void*)(void*)lb1, 16, 0, 0);
        __syncthreads();
        #pragma unroll
        for (int ks = 0; ks < 2; ++ks) {
            int slot = (ks * 4 + fq) ^ (fr & 7);
            half8 bf = *(const half8*)&Bs[(wave * 16 + fr) * 64 + slot * 8];
            #pragma unroll
            for (int mb = 0; mb < 4; ++mb) {
                half8 af = *(const half8*)&As[(mb * 16 + fr) * 64 + slot * 8];
                acc[mb] = __builtin_amdgcn_mfma_f32_16x16x32_f16(af, bf, acc[mb], 0, 0, 0);
            }
        }
        __syncthreads();
    }
    int col = n0 + wave * 16 + fr;
    float bv = ACT ? bias[col] : 0.f;
    float s_lo = 0.f, s_hi = 0.f;
    int blo = m0 / 961;
    int mcut = (blo + 1) * 961;
    #pragma unroll
    for (int mb = 0; mb < 4; ++mb) {
        #pragma unroll
        for (int r = 0; r < 4; ++r) {
            int m = m0 + mb * 16 + fq * 4 + r;
            if (m < M) {
                float v = acc[mb][r] + bv;
                if (ACT) v = (v >= 0.f) ? v : 0.01f * v;
                C[(size_t)m * Nc + col] = (OutT)v;
                if (DO_SUM) { if (m < mcut) s_lo += v; else s_hi += v; }
            }
        }
    }
    if (DO_SUM) {
        s_lo += __shfl_xor(s_lo, 16);
        s_lo += __shfl_xor(s_lo, 32);
        s_hi += __shfl_xor(s_hi, 16);
        s_hi += __shfl_xor(s_hi, 32);
        if (fq == 0) {
            atomicAdd(&S[blo * Nc + col], s_lo);
            int bhi = (m0 + 63) / 961;
            if (bhi != blo && bhi < NS) atomicAdd(&S[bhi * Nc + col], s_hi);
        }
    }
}

// K2: fused apply1 + GEMM2. Stages Z-tile and its +-PP neighbor tiles, computes
// H1-tile = lrelu(b1 + db*(db*(SZ+Z) + dm*Z[-PP] + dp*Z[+PP])) in LDS, MFMAs vs W2.
// Y raw out + per-sample colsums SY. Guard rows of Z (poison, finite) are only ever
// multiplied by an exactly-zero coefficient (dm=0 iff b=0; dp=0 iff b>=7).
__global__ __launch_bounds__(256) void gemm2_fused(
    const h16* __restrict__ Z,     // [m][HID], valid rows [0,MM); +-1024 guard rows exist
    const h16* __restrict__ B,     // W2 fp16 [OUTC][HID]
    const float* __restrict__ SZ,  // [NS][HID]
    const float* __restrict__ b1v, // [HID]
    float* __restrict__ C,         // Y [MM][OUTC] fp32
    float* __restrict__ SY)        // [NS][OUTC]
{
    __shared__ __align__(16) h16 Zc[64 * 64];
    __shared__ __align__(16) h16 Zm[64 * 64];
    __shared__ __align__(16) h16 Zp[64 * 64];
    __shared__ __align__(16) h16 Hs[64 * 64];
    __shared__ __align__(16) h16 Bs[64 * 64];
    int tid = threadIdx.x, wave = tid >> 6, lane = tid & 63;
    int m0 = blockIdx.x * 64, n0 = blockIdx.y * 64;
    int sro = lane >> 3;
    int sch = (lane & 7) ^ sro;
    const h16* gzc = Z + (ptrdiff_t)(m0 + wave * 16 + sro) * HID + sch * 8;
    const h16* gzm = gzc - (ptrdiff_t)PP * HID;
    const h16* gzp = gzc + (ptrdiff_t)PP * HID;
    const h16* gbb = B + (size_t)(n0 + wave * 16 + sro) * HID + sch * 8;
    h16* lzc0 = &Zc[(wave * 16) * 64];     h16* lzc1 = &Zc[(wave * 16 + 8) * 64];
    h16* lzm0 = &Zm[(wave * 16) * 64];     h16* lzm1 = &Zm[(wave * 16 + 8) * 64];
    h16* lzp0 = &Zp[(wave * 16) * 64];     h16* lzp1 = &Zp[(wave * 16 + 8) * 64];
    h16* lb0  = &Bs[(wave * 16) * 64];     h16* lb1  = &Bs[(wave * 16 + 8) * 64];
    int fr = lane & 15, fq = lane >> 4;
    // per-thread Hs chunks: q = tid*2, tid*2+1; both share row r
    int hr = tid >> 2;                      // row 0..63
    int hc0 = (tid & 3) * 2;                // chunks hc0, hc0+1
    int hm = m0 + hr;
    int hb = hm / PP; if (hb > NS - 1) hb = NS - 1;
    float db = dinv_of(hb);
    float dm = (hb > 0)      ? db * dinv_of(hb - 1) : 0.f;
    float dp = (hb < NS - 1) ? db * dinv_of(hb + 1) : 0.f;
    float db2 = db * db;
    floatx4 acc[4] = {{0.f,0.f,0.f,0.f},{0.f,0.f,0.f,0.f},{0.f,0.f,0.f,0.f},{0.f,0.f,0.f,0.f}};
    for (int kk = 0; kk < HID; kk += 64) {
        __builtin_amdgcn_global_load_lds((const AS1 void*)(const void*)(gzc + kk),
                                         (AS3 void*)(void*)lzc0, 16, 0, 0);
        __builtin_amdgcn_global_load_lds((const AS1 void*)(const void*)(gzc + 8 * HID + kk),
                                         (AS3 void*)(void*)lzc1, 16, 0, 0);
        __builtin_amdgcn_global_load_lds((const AS1 void*)(const void*)(gzm + kk),
                                         (AS3 void*)(void*)lzm0, 16, 0, 0);
        __builtin_amdgcn_global_load_lds((const AS1 void*)(const void*)(gzm + 8 * HID + kk),
                                         (AS3 void*)(void*)lzm1, 16, 0, 0);
        __builtin_amdgcn_global_load_lds((const AS1 void*)(const void*)(gzp + kk),
                                         (AS3 void*)(void*)lzp0, 16, 0, 0);
        __builtin_amdgcn_global_load_lds((const AS1 void*)(const void*)(gzp + 8 * HID + kk),
                                         (AS3 void*)(void*)lzp1, 16, 0, 0);
        __builtin_amdgcn_global_load_lds((const AS1 void*)(const void*)(gbb + kk),
                                         (AS3 void*)(void*)lb0, 16, 0, 0);
        __builtin_amdgcn_global_load_lds((const AS1 void*)(const void*)(gbb + 8 * HID + kk),
                                         (AS3 void*)(void*)lb1, 16, 0, 0);
        __syncthreads();
        // compute H1 chunks in LDS
        #pragma unroll
        for (int qi = 0; qi < 2; ++qi) {
            int ch = hc0 + qi;
            int slot = ch ^ (hr & 7);
            int off = hr * 64 + slot * 8;
            half8 zc = *(const half8*)&Zc[off];
            half8 zm = *(const half8*)&Zm[off];
            half8 zp = *(const half8*)&Zp[off];
            int h0 = kk + ch * 8;
            float4 s0  = *(const float4*)(SZ + hb * HID + h0);
            float4 s1  = *(const float4*)(SZ + hb * HID + h0 + 4);
            float4 bb0 = *(const float4*)(b1v + h0);
            float4 bb1 = *(const float4*)(b1v + h0 + 4);
            float ss[8] = {s0.x, s0.y, s0.z, s0.w, s1.x, s1.y, s1.z, s1.w};
            float bb[8] = {bb0.x, bb0.y, bb0.z, bb0.w, bb1.x, bb1.y, bb1.z, bb1.w};
            half8 o;
            #pragma unroll
            for (int j = 0; j < 8; ++j) {
                float v = db2 * (ss[j] + (float)zc[j])
                        + dm * (float)zm[j] + dp * (float)zp[j] + bb[j];
                v = (v >= 0.f) ? v : 0.01f * v;
                o[j] = (h16)v;
            }
            *(half8*)&Hs[off] = o;
        }
        __syncthreads();
        #pragma unroll
        for (int ks = 0; ks < 2; ++ks) {
            int slot = (ks * 4 + fq) ^ (fr & 7);
            half8 bf = *(const half8*)&Bs[(wave * 16 + fr) * 64 + slot * 8];
            #pragma unroll
            for (int mb = 0; mb < 4; ++mb) {
                half8 af = *(const half8*)&Hs[(mb * 16 + fr) * 64 + slot * 8];
                acc[mb] = __builtin_amdgcn_mfma_f32_16x16x32_f16(af, bf, acc[mb], 0, 0, 0);
            }
        }
        __syncthreads();
    }
    int col = n0 + wave * 16 + fr;
    float s_lo = 0.f, s_hi = 0.f;
    int blo = m0 / 961;
    int mcut = (blo + 1) * 961;
    #pragma unroll
    for (int mb = 0; mb < 4; ++mb) {
        #pragma unroll
        for (int r = 0; r < 4; ++r) {
            int m = m0 + mb * 16 + fq * 4 + r;
            if (m < MM) {
                float v = acc[mb][r];
                C[(size_t)m * OUTC + col] = v;
                if (m < mcut) s_lo += v; else s_hi += v;
            }
        }
    }
    s_lo += __shfl_xor(s_lo, 16);
    s_lo += __shfl_xor(s_lo, 32);
    s_hi += __shfl_xor(s_hi, 16);
    s_hi += __shfl_xor(s_hi, 32);
    if (fq == 0) {
        atomicAdd(&SY[blo * OUTC + col], s_lo);
        int bhi = (m0 + 63) / 961;
        if (bhi != blo && bhi < NS) atomicAdd(&SY[bhi * OUTC + col], s_hi);
    }
}

// K3: out[o*PP+p] = max_b lrelu( b2[o] + db*( db*(SY[b,o]+Y[b,p,o]) + dm*Y[b-1,p,o] + dp*Y[b+1,p,o] ) )
__global__ void final_max(const float* __restrict__ Y, const float* __restrict__ SY,
                          const float* __restrict__ b2, float* __restrict__ out) {
    int pt = blockIdx.x, ot = blockIdx.y;
    int p0 = pt * 32, o0 = ot * 32;
    __shared__ float t[32][33];
    int i = threadIdx.x & 31, j0 = threadIdx.x >> 5;
    int o = o0 + i;
    float bias = b2[o];
    #pragma unroll
    for (int r = 0; r < 4; ++r) {
        int j = j0 + r * 8;
        int p = p0 + j;
        float vmax = -INFINITY;
        if (p < PP) {
            float y[NS];
            #pragma unroll
            for (int b = 0; b < NS; ++b)
                y[b] = Y[((size_t)b * PP + p) * OUTC + o];
            #pragma unroll
            for (int b = 0; b < NS; ++b) {
                float db = dinv_of(b);
                float a = db * (SY[b * OUTC + o] + y[b]);
                if (b > 0)      a += dinv_of(b - 1) * y[b - 1];
                if (b < NS - 1) a += dinv_of(b + 1) * y[b + 1];
                float z = db * a + bias;
                z = (z >= 0.f) ? z : 0.01f * z;
                vmax = fmaxf(vmax, z);
            }
        }
        t[j][i] = vmax;
    }
    __syncthreads();
    int jj = threadIdx.x & 31, ii0 = threadIdx.x >> 5;
    #pragma unroll
    for (int r = 0; r < 4; ++r) {
        int ii = ii0 + r * 8;
        int pw = p0 + jj;
        if (pw < PP)
            out[(size_t)(o0 + ii) * PP + pw] = t[jj][ii];
    }
}

extern "C" void kernel_launch(void* const* d_in, const int* in_sizes, int n_in,
                              void* d_out, int out_size, void* d_ws, size_t ws_size,
                              hipStream_t stream) {
    const float* x  = (const float*)d_in[0];
    const float* W1 = (const float*)d_in[1];
    const float* b1 = (const float*)d_in[2];
    const float* W2 = (const float*)d_in[3];
    const float* b2 = (const float*)d_in[4];
    float* out = (float*)d_out;
    float* ws  = (float*)d_ws;

    // workspace layout (float offsets, 16B-aligned)
    float* SZ  = ws;                             //     4,096 f
    float* SY  = ws + 4096;                      //     2,048 f
    h16*  w1h  = (h16*)(ws + 6144);              //  131,072 h = 65,536 f
    h16*  w2h  = (h16*)(ws + 71680);             //  131,072 h
    h16*  Xt   = (h16*)(ws + 137216);            //  MP*CC h = 991,232 f
    h16*  Zbuf = (h16*)(ws + 1128448);           //  (1024+MP+1024)*HID h = 2,506,752 f
    h16*  Z    = Zbuf + (size_t)1024 * HID;      //  valid rows [0, MP)
    float* Y   = ws + 3635200;                   //  MM*OUTC f = 1,968,128 f -> end 5,603,328 f (22.4 MB)

    prep<<<2264, 256, 0, stream>>>(W1, W2, w1h, w2h, x, Xt, SZ, SY);
    mfma_gemm<CC, false, true, h16><<<dim3(MP / 64, HID / 64), 256, 0, stream>>>(
        Xt, w1h, nullptr, Z, SZ, MM, HID);
    gemm2_fused<<<dim3(MP / 64, OUTC / 64), 256, 0, stream>>>(Z, w2h, SZ, b1, Y, SY);
    final_max<<<dim3(31, 8), 256, 0, stream>>>(Y, SY, b2, out);
}